// Round 3
// baseline (582.371 us; speedup 1.0000x reference)
//
#include <hip/hip_runtime.h>
#include <stdint.h>
#include <stddef.h>

// Problem constants
#define BN 16
#define CN 128
#define HN 56
#define WN 56
#define HWN 3136            // H*W
#define FN 9                // K*K deformation taps
#define DN 18               // 2*F offset channels
#define ON 512              // OUT
#define KN 1152             // F*C  (GEMM K)
#define MN 50176            // B*H*W (GEMM M)
#define MB 128              // m per fused block

typedef __bf16 bf16x8 __attribute__((ext_vector_type(8)));
typedef float f32x4 __attribute__((ext_vector_type(4)));

__device__ __forceinline__ unsigned short f2bf(float f) {
  unsigned int u = __builtin_bit_cast(unsigned int, f);
  u += 0x7fffu + ((u >> 16) & 1u);   // round-to-nearest-even
  return (unsigned short)(u >> 16);
}

// ---------------- Phase 0a: x fp32 [B,C,HW] -> xt bf16 [B,HW,C] ----------------
__global__ void k_transpose(const float* __restrict__ x, unsigned short* __restrict__ xt) {
  __shared__ float tile[32][33];
  const int b = blockIdx.z;
  const int hw0 = blockIdx.x * 32;   // 3136/32 = 98 exact
  const int c0 = blockIdx.y * 32;    // 128/32 = 4 exact
  const int tx = threadIdx.x & 31;
  const int ty = threadIdx.x >> 5;   // 0..7
  const float* xb = x + (size_t)b * CN * HWN;
  unsigned short* xtb = xt + (size_t)b * HWN * CN;
#pragma unroll
  for (int r = 0; r < 4; ++r)
    tile[ty + r * 8][tx] = xb[(size_t)(c0 + ty + r * 8) * HWN + hw0 + tx];
  __syncthreads();
#pragma unroll
  for (int r = 0; r < 4; ++r)
    xtb[(size_t)(hw0 + ty + r * 8) * CN + c0 + tx] = f2bf(tile[tx][ty + r * 8]);
}

// ---------------- Phase 0b: w_conv fp32 -> bf16 ----------------
__global__ void k_wconv(const float4* __restrict__ w, ushort4* __restrict__ wb) {
  const int i = blockIdx.x * 256 + threadIdx.x;  // 512*1152/4 = 147456 exact
  float4 v = w[i];
  ushort4 o;
  o.x = f2bf(v.x); o.y = f2bf(v.y); o.z = f2bf(v.z); o.w = f2bf(v.w);
  wb[i] = o;
}

// ---------------- Phase 1: per-pixel offset conv -> (ix,iy) per tap ------------
__global__ void k_offsets(const unsigned short* __restrict__ xt, const float* __restrict__ w_off,
                          const float* __restrict__ b_off, float2* __restrict__ ixy) {
  __shared__ float lwoff[DN * CN];
  __shared__ float lboff[DN];
  for (int i = threadIdx.x; i < DN * CN; i += 256) lwoff[i] = w_off[i];
  if (threadIdx.x < DN) lboff[threadIdx.x] = b_off[threadIdx.x];
  __syncthreads();

  const int m = blockIdx.x * 256 + threadIdx.x;  // 50176 = 196*256 exact
  const int b = m / HWN;
  const int hw = m - b * HWN;
  const int h = hw / WN;
  const int w = hw - h * WN;
  const unsigned short* xp = xt + (size_t)m * CN;
  float acc[DN];
#pragma unroll
  for (int d = 0; d < DN; ++d) acc[d] = lboff[d];
  for (int c = 0; c < CN; c += 8) {
    bf16x8 xv = *(const bf16x8*)(xp + c);
    float xf[8];
#pragma unroll
    for (int q = 0; q < 8; ++q) xf[q] = (float)xv[q];
#pragma unroll
    for (int d = 0; d < DN; ++d) {
      float4 w0 = *(const float4*)(lwoff + d * CN + c);      // uniform -> broadcast
      float4 w1 = *(const float4*)(lwoff + d * CN + c + 4);
      acc[d] += xf[0] * w0.x + xf[1] * w0.y + xf[2] * w0.z + xf[3] * w0.w
              + xf[4] * w1.x + xf[5] * w1.y + xf[6] * w1.z + xf[7] * w1.w;
    }
  }
  const float scale = 2.0f / 56.0f;
  const float bx = (2.0f * w + 1.0f) / (float)WN - 1.0f;
  const float by = (2.0f * h + 1.0f) / (float)HN - 1.0f;
#pragma unroll
  for (int f = 0; f < FN; ++f) {
    float gx = bx + acc[2 * f] * scale;
    float gy = by + acc[2 * f + 1] * scale;
    float ixv = ((gx + 1.0f) * (float)WN - 1.0f) * 0.5f;
    float iyv = ((gy + 1.0f) * (float)HN - 1.0f) * 0.5f;
    ixy[(size_t)m * FN + f] = make_float2(ixv, iyv);
  }
}

// ---------------- Phase 2: FUSED sample + GEMM -----------------------------------
// out[o,m] = sum_k Wb[o,k]*S[m,k] + bias[o], S built on the fly per K-tile.
// K-tile kt covers exactly tap f=kt>>1, channel-half h=kt&1 (64 ch).
// Block: 512o x 128m, 8 waves (4 wm x 2 wn), wave tile 128o x 64m.
// A (W, 1.1 MB total) gathered DIRECTLY from global (L2-resident; no LDS, no A dup).
// B: built by bilinear sampling xt into a 16 KiB LDS tile, double-buffered.
// LDS 41 KiB, 1 barrier per K-tile. R1/R2 post-mortem: schedule variants all stall
// ~60% of CU time; the build work hides in those stalls and S (115.6 MB HBM
// round-trip + k_sample kernel) disappears entirely.
__global__ __launch_bounds__(512, 2) void k_fused(const unsigned short* __restrict__ Wb,
                                                  const unsigned short* __restrict__ xt,
                                                  const float2* __restrict__ ixy,
                                                  const float* __restrict__ bias,
                                                  float* __restrict__ out) {
  __shared__ __align__(16) char smem[41984];
  // [0,16384): B buf0 ; [16384,32768): B buf1 ; [32768,41984): ixy cache
  float2* lixy = (float2*)(smem + 32768);
  const int tid = threadIdx.x;
  const int wave = tid >> 6;
  const int lane = tid & 63;
  const int quad = lane >> 4;
  const int r16 = lane & 15;
  const int wm = wave >> 1;          // 0..3 (o)
  const int wn = wave & 1;           // 0..1 (m)

  // XCD-bijective swizzle (392 = 8*49 exact): neighboring m-tiles share an XCD
  // -> corner reads of adjacent spatial rows hit the same L2.
  const int bid = blockIdx.x;
  const int wgid = (bid & 7) * 49 + (bid >> 3);
  const int m0 = wgid * MB;

  // stage this block's ixy slice (contiguous [m0*9, +1152) float2, coalesced)
  for (int i = tid; i < MB * FN; i += 512) lixy[i] = ixy[(size_t)m0 * FN + i];

  // build-thread constants: thread -> (m-local, 16-ch slice)
  const int bm = tid >> 2;            // 0..127
  const int bc = (tid & 3) * 16;      // ch offset within the 64-ch half
  const int gm = m0 + bm;
  const int bb = gm / HWN;
  const unsigned short* xb = xt + (size_t)bb * HWN * CN;

  f32x4 acc[8][4];
#pragma unroll
  for (int i = 0; i < 8; ++i)
#pragma unroll
    for (int j = 0; j < 4; ++j) acc[i][j] = (f32x4){0.f, 0.f, 0.f, 0.f};

  const int rsw = r16 & 15 & 7;
  const int b_row = (wn * 64 + r16) * 128;                       // byte row base in B tile
  const unsigned short* aP = Wb + (size_t)(wm * 128 + r16) * KN + quad * 8;

  // Build one 128m x 64ch B tile (tap f, half h) into LDS with chunk-XOR swizzle.
  // Write: global chunk c stored at (c ^ (row&7)). 8-lane groups hit 8 distinct
  // chunks -> conflict-free (verified: (2cp)^(m&7) is a bijection per group).
#define BUILD(DST, KT) do {                                                        \
    const int f_ = (KT) >> 1, h_ = (KT) & 1;                                       \
    const float2 p_ = lixy[bm * FN + f_];                                          \
    const float ix_ = p_.x, iy_ = p_.y;                                            \
    const float x0f = floorf(ix_), y0f = floorf(iy_);                              \
    const float wx1 = ix_ - x0f, wy1 = iy_ - y0f;                                  \
    const float wx0 = 1.0f - wx1, wy0 = 1.0f - wy1;                                \
    const int x0 = (int)x0f, y0 = (int)y0f;                                        \
    const int x1 = x0 + 1, y1 = y0 + 1;                                            \
    const bool vx0 = (x0 >= 0) & (x0 < WN), vx1 = (x1 >= 0) & (x1 < WN);           \
    const bool vy0 = (y0 >= 0) & (y0 < HN), vy1 = (y1 >= 0) & (y1 < HN);           \
    const float w00 = wy0 * wx0 * ((vy0 & vx0) ? 1.0f : 0.0f);                     \
    const float w01 = wy0 * wx1 * ((vy0 & vx1) ? 1.0f : 0.0f);                     \
    const float w10 = wy1 * wx0 * ((vy1 & vx0) ? 1.0f : 0.0f);                     \
    const float w11 = wy1 * wx1 * ((vy1 & vx1) ? 1.0f : 0.0f);                     \
    const int x0c = min(max(x0, 0), WN - 1), x1c = min(max(x1, 0), WN - 1);        \
    const int y0c = min(max(y0, 0), HN - 1), y1c = min(max(y1, 0), HN - 1);        \
    const unsigned short* cp_ = xb + h_ * 64 + bc;                                 \
    const bf16x8* q00 = (const bf16x8*)(cp_ + (size_t)(y0c * WN + x0c) * CN);      \
    const bf16x8* q01 = (const bf16x8*)(cp_ + (size_t)(y0c * WN + x1c) * CN);      \
    const bf16x8* q10 = (const bf16x8*)(cp_ + (size_t)(y1c * WN + x0c) * CN);      \
    const bf16x8* q11 = (const bf16x8*)(cp_ + (size_t)(y1c * WN + x1c) * CN);      \
    bf16x8 A0 = q00[0], A1 = q00[1];                                               \
    bf16x8 B0 = q01[0], B1 = q01[1];                                               \
    bf16x8 C0 = q10[0], C1 = q10[1];                                               \
    bf16x8 D0 = q11[0], D1 = q11[1];                                               \
    unsigned short ov[16];                                                         \
    _Pragma("unroll") for (int q_ = 0; q_ < 8; ++q_) {                             \
      float lo = w00 * (float)A0[q_] + w01 * (float)B0[q_]                         \
               + w10 * (float)C0[q_] + w11 * (float)D0[q_];                        \
      float hi = w00 * (float)A1[q_] + w01 * (float)B1[q_]                         \
               + w10 * (float)C1[q_] + w11 * (float)D1[q_];                        \
      ov[q_] = f2bf(lo);                                                           \
      ov[q_ + 8] = f2bf(hi);                                                       \
    }                                                                              \
    const int c0_ = (tid & 3) * 2;                                                 \
    *(uint4*)(smem + (DST) + bm * 128 + ((c0_ ^ (bm & 7)) * 16)) =                 \
        *(const uint4*)(ov);                                                       \
    *(uint4*)(smem + (DST) + bm * 128 + (((c0_ + 1) ^ (bm & 7)) * 16)) =           \
        *(const uint4*)(ov + 8);                                                   \
  } while (0)

  // A fragments (8 x bf16x8) straight from global: rows wm*128+i*16+r16,
  // k = kt*64 + h*32 + quad*8. W is L2-resident after first blocks touch it.
#define LOADA(AV, KT, H) do {                                                      \
    _Pragma("unroll") for (int i_ = 0; i_ < 8; ++i_)                               \
      AV[i_] = *(const bf16x8*)(aP + (size_t)i_ * 16 * KN + (KT) * 64 + (H) * 32); \
  } while (0)

  // B fragment reads (4 x ds_read_b128, conflict-free per 8-lane group) + 32 MFMA
#define AB_MFMA(PARB, H, AV) do {                                                  \
    const char* bb_ = smem + (PARB) + b_row;                                       \
    bf16x8 bv[4];                                                                  \
    _Pragma("unroll") for (int j_ = 0; j_ < 4; ++j_)                               \
      bv[j_] = *(const bf16x8*)(bb_ + j_ * 16 * 128 + ((((H) * 4 + quad) ^ rsw) * 16)); \
    __builtin_amdgcn_s_setprio(1);                                                 \
    _Pragma("unroll") for (int i_ = 0; i_ < 8; ++i_)                               \
    _Pragma("unroll") for (int j_ = 0; j_ < 4; ++j_)                               \
      acc[i_][j_] = __builtin_amdgcn_mfma_f32_16x16x32_bf16(AV[i_], bv[j_],        \
                                                            acc[i_][j_], 0, 0, 0); \
    __builtin_amdgcn_s_setprio(0);                                                 \
  } while (0)

  __syncthreads();            // lixy ready
  BUILD(0, 0);                // prologue: tile 0 -> buf0
  __syncthreads();

#pragma unroll 1
  for (int kt = 0; kt < 18; ++kt) {
    const int PAR = (kt & 1) * 16384;
    bf16x8 a0v[8], a1v[8];
    LOADA(a0v, kt, 0);                      // A h0 in flight during build
    if (kt < 17) BUILD(16384 - PAR, kt + 1);  // next tile -> other buffer
    LOADA(a1v, kt, 1);                      // A h1 in flight during MFMA h0
    AB_MFMA(PAR, 0, a0v);
    AB_MFMA(PAR, 1, a1v);
    __syncthreads();   // build(kt+1) visible to next iter; WAR on buffer PAR
  }

  // Epilogue: 16 rounds of 32 o-rows x 128 m fp32 staged in LDS (stride 132
  // breaks quad-row bank alias), then full float4 lines to global.
  // C/D layout: col(m)=r16, row(o)=quad*4+reg.
  float* lout = (float*)smem;
  const int LSTR = 132;
#pragma unroll 1
  for (int ob = 0; ob < 16; ++ob) {
    __syncthreads();
    if (wm == (ob >> 2)) {
#pragma unroll
      for (int il = 0; il < 2; ++il) {
        const int i = (ob & 3) * 2 + il;
#pragma unroll
        for (int j = 0; j < 4; ++j) {
          f32x4 v = acc[i][j];
          const int col = wn * 64 + j * 16 + r16;
          const int rb = il * 16 + quad * 4;
          lout[(rb + 0) * LSTR + col] = v[0];
          lout[(rb + 1) * LSTR + col] = v[1];
          lout[(rb + 2) * LSTR + col] = v[2];
          lout[(rb + 3) * LSTR + col] = v[3];
        }
      }
    }
    __syncthreads();
#pragma unroll
    for (int tl = 0; tl < 2; ++tl) {
      const int idx = tl * 512 + tid;       // 1024 f4 = 32 rows x 32 f4
      const int orow = idx >> 5, c4 = idx & 31;
      float4 v = *(const float4*)(lout + orow * LSTR + c4 * 4);
      const int o = ob * 32 + orow;
      const float bv = bias[o];
      v.x += bv; v.y += bv; v.z += bv; v.w += bv;
      const int p = m0 + c4 * 4;
      const int bidx = p / HWN;             // 3136 % 4 == 0 -> no b straddle
      const int hw = p - bidx * HWN;
      *(float4*)(out + (size_t)bidx * ON * HWN + (size_t)o * HWN + hw) = v;
    }
  }
#undef BUILD
#undef LOADA
#undef AB_MFMA
}

extern "C" void kernel_launch(void* const* d_in, const int* in_sizes, int n_in,
                              void* d_out, int out_size, void* d_ws, size_t ws_size,
                              hipStream_t stream) {
  const float* x = (const float*)d_in[0];       // [16,128,56,56]
  const float* w_off = (const float*)d_in[1];   // [18,128]
  const float* b_off = (const float*)d_in[2];   // [18]
  const float* w_conv = (const float*)d_in[3];  // [512,1152]
  const float* b_conv = (const float*)d_in[4];  // [512]
  float* out = (float*)d_out;                   // [16,512,56,56] fp32

  // workspace layout (16B aligned):
  //   xt  : bf16 [B,HW,C]      12,845,056 B @ 0
  //   Wb  : bf16 [512,1152]     1,179,648 B @ 12,845,056
  //   ixy : float2 [M,F]        3,612,672 B @ 14,024,704   (total ~17.6 MB)
  char* ws = (char*)d_ws;
  unsigned short* xt = (unsigned short*)(ws);
  unsigned short* Wb = (unsigned short*)(ws + 12845056);
  float2* ixy = (float2*)(ws + 14024704);

  k_transpose<<<dim3(98, 4, 16), 256, 0, stream>>>(x, xt);
  k_wconv<<<dim3(576), 256, 0, stream>>>((const float4*)w_conv, (ushort4*)Wb);
  k_offsets<<<dim3(196), 256, 0, stream>>>(xt, w_off, b_off, ixy);
  k_fused<<<dim3(392), 512, 0, stream>>>(Wb, xt, ixy, b_conv, out);
}

// Round 4
// 325.234 us; speedup vs baseline: 1.7906x; 1.7906x over previous
//
#include <hip/hip_runtime.h>
#include <stdint.h>
#include <stddef.h>

// Problem constants
#define BN 16
#define CN 128
#define HN 56
#define WN 56
#define HWN 3136            // H*W
#define FN 9                // K*K deformation taps
#define DN 18               // 2*F offset channels
#define ON 512              // OUT
#define KN 1152             // F*C  (GEMM K)
#define MN 50176            // B*H*W (GEMM M)
#define MB 128              // m per fused block

typedef __bf16 bf16x8 __attribute__((ext_vector_type(8)));
typedef float f32x4 __attribute__((ext_vector_type(4)));

__device__ __forceinline__ unsigned short f2bf(float f) {
  unsigned int u = __builtin_bit_cast(unsigned int, f);
  u += 0x7fffu + ((u >> 16) & 1u);   // round-to-nearest-even
  return (unsigned short)(u >> 16);
}

// ---------------- Phase 0a: x fp32 [B,C,HW] -> xt bf16 [B,HW,C] ----------------
__global__ void k_transpose(const float* __restrict__ x, unsigned short* __restrict__ xt) {
  __shared__ float tile[32][33];
  const int b = blockIdx.z;
  const int hw0 = blockIdx.x * 32;   // 3136/32 = 98 exact
  const int c0 = blockIdx.y * 32;    // 128/32 = 4 exact
  const int tx = threadIdx.x & 31;
  const int ty = threadIdx.x >> 5;   // 0..7
  const float* xb = x + (size_t)b * CN * HWN;
  unsigned short* xtb = xt + (size_t)b * HWN * CN;
#pragma unroll
  for (int r = 0; r < 4; ++r)
    tile[ty + r * 8][tx] = xb[(size_t)(c0 + ty + r * 8) * HWN + hw0 + tx];
  __syncthreads();
#pragma unroll
  for (int r = 0; r < 4; ++r)
    xtb[(size_t)(hw0 + ty + r * 8) * CN + c0 + tx] = f2bf(tile[tx][ty + r * 8]);
}

// ---------------- Phase 0b: w_conv fp32 -> bf16 ----------------
__global__ void k_wconv(const float4* __restrict__ w, ushort4* __restrict__ wb) {
  const int i = blockIdx.x * 256 + threadIdx.x;  // 512*1152/4 = 147456 exact
  float4 v = w[i];
  ushort4 o;
  o.x = f2bf(v.x); o.y = f2bf(v.y); o.z = f2bf(v.z); o.w = f2bf(v.w);
  wb[i] = o;
}

// ---------------- Phase 1: per-pixel offset conv -> (ix,iy) per tap ------------
__global__ void k_offsets(const unsigned short* __restrict__ xt, const float* __restrict__ w_off,
                          const float* __restrict__ b_off, float2* __restrict__ ixy) {
  __shared__ float lwoff[DN * CN];
  __shared__ float lboff[DN];
  for (int i = threadIdx.x; i < DN * CN; i += 256) lwoff[i] = w_off[i];
  if (threadIdx.x < DN) lboff[threadIdx.x] = b_off[threadIdx.x];
  __syncthreads();

  const int m = blockIdx.x * 256 + threadIdx.x;  // 50176 = 196*256 exact
  const int b = m / HWN;
  const int hw = m - b * HWN;
  const int h = hw / WN;
  const int w = hw - h * WN;
  const unsigned short* xp = xt + (size_t)m * CN;
  float acc[DN];
#pragma unroll
  for (int d = 0; d < DN; ++d) acc[d] = lboff[d];
  for (int c = 0; c < CN; c += 8) {
    bf16x8 xv = *(const bf16x8*)(xp + c);
    float xf[8];
#pragma unroll
    for (int q = 0; q < 8; ++q) xf[q] = (float)xv[q];
#pragma unroll
    for (int d = 0; d < DN; ++d) {
      float4 w0 = *(const float4*)(lwoff + d * CN + c);      // uniform -> broadcast
      float4 w1 = *(const float4*)(lwoff + d * CN + c + 4);
      acc[d] += xf[0] * w0.x + xf[1] * w0.y + xf[2] * w0.z + xf[3] * w0.w
              + xf[4] * w1.x + xf[5] * w1.y + xf[6] * w1.z + xf[7] * w1.w;
    }
  }
  const float scale = 2.0f / 56.0f;
  const float bx = (2.0f * w + 1.0f) / (float)WN - 1.0f;
  const float by = (2.0f * h + 1.0f) / (float)HN - 1.0f;
#pragma unroll
  for (int f = 0; f < FN; ++f) {
    float gx = bx + acc[2 * f] * scale;
    float gy = by + acc[2 * f + 1] * scale;
    float ixv = ((gx + 1.0f) * (float)WN - 1.0f) * 0.5f;
    float iyv = ((gy + 1.0f) * (float)HN - 1.0f) * 0.5f;
    ixy[(size_t)m * FN + f] = make_float2(ixv, iyv);
  }
}

// ---------------- Phase 2: FUSED sample + GEMM -----------------------------------
// out[o,m] = sum_k Wb[o,k]*S[m,k] + bias[o], S built on the fly per K-tile.
// K-tile kt covers exactly tap f=kt>>1, channel-half h=kt&1 (64 ch).
// Block: 512o x 128m, 8 waves (4 wm x 2 wn), wave tile 128o x 64m.
// A (W, 1.1 MB total) gathered DIRECTLY from global (L2-resident; no LDS, no A dup).
// B: built by bilinear sampling xt into a 16 KiB LDS tile, double-buffered.
// R3 post-mortem: the ONLY bug was `#pragma unroll 1` on the epilogue -> runtime
// acc indexing -> whole accumulator demoted to scratch (WRITE_SIZE 2 GB, rule #20).
// Fix: fully unroll the epilogue so every acc access is compile-time-constant.
__global__ __launch_bounds__(512, 2) void k_fused(const unsigned short* __restrict__ Wb,
                                                  const unsigned short* __restrict__ xt,
                                                  const float2* __restrict__ ixy,
                                                  const float* __restrict__ bias,
                                                  float* __restrict__ out) {
  __shared__ __align__(16) char smem[41984];
  // [0,16384): B buf0 ; [16384,32768): B buf1 ; [32768,41984): ixy cache
  float2* lixy = (float2*)(smem + 32768);
  const int tid = threadIdx.x;
  const int wave = tid >> 6;
  const int lane = tid & 63;
  const int quad = lane >> 4;
  const int r16 = lane & 15;
  const int wm = wave >> 1;          // 0..3 (o)
  const int wn = wave & 1;           // 0..1 (m)

  // XCD-bijective swizzle (392 = 8*49 exact): neighboring m-tiles share an XCD
  // -> corner reads of adjacent spatial rows hit the same L2.
  const int bid = blockIdx.x;
  const int wgid = (bid & 7) * 49 + (bid >> 3);
  const int m0 = wgid * MB;

  // stage this block's ixy slice (contiguous [m0*9, +1152) float2, coalesced)
  for (int i = tid; i < MB * FN; i += 512) lixy[i] = ixy[(size_t)m0 * FN + i];

  // build-thread constants: thread -> (m-local, 16-ch slice)
  const int bm = tid >> 2;            // 0..127
  const int bc = (tid & 3) * 16;      // ch offset within the 64-ch half
  const int gm = m0 + bm;
  const int bb = gm / HWN;
  const unsigned short* xb = xt + (size_t)bb * HWN * CN;

  f32x4 acc[8][4];
#pragma unroll
  for (int i = 0; i < 8; ++i)
#pragma unroll
    for (int j = 0; j < 4; ++j) acc[i][j] = (f32x4){0.f, 0.f, 0.f, 0.f};

  const int rsw = r16 & 7;
  const int b_row = (wn * 64 + r16) * 128;                       // byte row base in B tile
  const unsigned short* aP = Wb + (size_t)(wm * 128 + r16) * KN + quad * 8;

  // Build one 128m x 64ch B tile (tap f, half h) into LDS with chunk-XOR swizzle.
  // Write: global chunk c stored at (c ^ (row&7)). 8-lane groups hit 8 distinct
  // chunks -> conflict-free.
#define BUILD(DST, KT) do {                                                        \
    const int f_ = (KT) >> 1, h_ = (KT) & 1;                                       \
    const float2 p_ = lixy[bm * FN + f_];                                          \
    const float ix_ = p_.x, iy_ = p_.y;                                            \
    const float x0f = floorf(ix_), y0f = floorf(iy_);                              \
    const float wx1 = ix_ - x0f, wy1 = iy_ - y0f;                                  \
    const float wx0 = 1.0f - wx1, wy0 = 1.0f - wy1;                                \
    const int x0 = (int)x0f, y0 = (int)y0f;                                        \
    const int x1 = x0 + 1, y1 = y0 + 1;                                            \
    const bool vx0 = (x0 >= 0) & (x0 < WN), vx1 = (x1 >= 0) & (x1 < WN);           \
    const bool vy0 = (y0 >= 0) & (y0 < HN), vy1 = (y1 >= 0) & (y1 < HN);           \
    const float w00 = wy0 * wx0 * ((vy0 & vx0) ? 1.0f : 0.0f);                     \
    const float w01 = wy0 * wx1 * ((vy0 & vx1) ? 1.0f : 0.0f);                     \
    const float w10 = wy1 * wx0 * ((vy1 & vx0) ? 1.0f : 0.0f);                     \
    const float w11 = wy1 * wx1 * ((vy1 & vx1) ? 1.0f : 0.0f);                     \
    const int x0c = min(max(x0, 0), WN - 1), x1c = min(max(x1, 0), WN - 1);        \
    const int y0c = min(max(y0, 0), HN - 1), y1c = min(max(y1, 0), HN - 1);        \
    const unsigned short* cp_ = xb + h_ * 64 + bc;                                 \
    const bf16x8* q00 = (const bf16x8*)(cp_ + (size_t)(y0c * WN + x0c) * CN);      \
    const bf16x8* q01 = (const bf16x8*)(cp_ + (size_t)(y0c * WN + x1c) * CN);      \
    const bf16x8* q10 = (const bf16x8*)(cp_ + (size_t)(y1c * WN + x0c) * CN);      \
    const bf16x8* q11 = (const bf16x8*)(cp_ + (size_t)(y1c * WN + x1c) * CN);      \
    bf16x8 A0 = q00[0], A1 = q00[1];                                               \
    bf16x8 B0 = q01[0], B1 = q01[1];                                               \
    bf16x8 C0 = q10[0], C1 = q10[1];                                               \
    bf16x8 D0 = q11[0], D1 = q11[1];                                               \
    unsigned short ov[16];                                                         \
    _Pragma("unroll") for (int q_ = 0; q_ < 8; ++q_) {                             \
      float lo = w00 * (float)A0[q_] + w01 * (float)B0[q_]                         \
               + w10 * (float)C0[q_] + w11 * (float)D0[q_];                        \
      float hi = w00 * (float)A1[q_] + w01 * (float)B1[q_]                         \
               + w10 * (float)C1[q_] + w11 * (float)D1[q_];                        \
      ov[q_] = f2bf(lo);                                                           \
      ov[q_ + 8] = f2bf(hi);                                                       \
    }                                                                              \
    const int c0_ = (tid & 3) * 2;                                                 \
    *(uint4*)(smem + (DST) + bm * 128 + ((c0_ ^ (bm & 7)) * 16)) =                 \
        *(const uint4*)(ov);                                                       \
    *(uint4*)(smem + (DST) + bm * 128 + (((c0_ + 1) ^ (bm & 7)) * 16)) =           \
        *(const uint4*)(ov + 8);                                                   \
  } while (0)

  // A fragments (8 x bf16x8) straight from global: rows wm*128+i*16+r16,
  // k = kt*64 + h*32 + quad*8. W is L2-resident after first blocks touch it.
#define LOADA(AV, KT, H) do {                                                      \
    _Pragma("unroll") for (int i_ = 0; i_ < 8; ++i_)                               \
      AV[i_] = *(const bf16x8*)(aP + (size_t)i_ * 16 * KN + (KT) * 64 + (H) * 32); \
  } while (0)

  // B fragment reads (4 x ds_read_b128, conflict-free per 8-lane group) + 32 MFMA
#define AB_MFMA(PARB, H, AV) do {                                                  \
    const char* bb_ = smem + (PARB) + b_row;                                       \
    bf16x8 bv[4];                                                                  \
    _Pragma("unroll") for (int j_ = 0; j_ < 4; ++j_)                               \
      bv[j_] = *(const bf16x8*)(bb_ + j_ * 16 * 128 + ((((H) * 4 + quad) ^ rsw) * 16)); \
    __builtin_amdgcn_s_setprio(1);                                                 \
    _Pragma("unroll") for (int i_ = 0; i_ < 8; ++i_)                               \
    _Pragma("unroll") for (int j_ = 0; j_ < 4; ++j_)                               \
      acc[i_][j_] = __builtin_amdgcn_mfma_f32_16x16x32_bf16(AV[i_], bv[j_],        \
                                                            acc[i_][j_], 0, 0, 0); \
    __builtin_amdgcn_s_setprio(0);                                                 \
  } while (0)

  __syncthreads();            // lixy ready
  BUILD(0, 0);                // prologue: tile 0 -> buf0
  __syncthreads();

#pragma unroll 1
  for (int kt = 0; kt < 18; ++kt) {
    const int PAR = (kt & 1) * 16384;
    bf16x8 a0v[8], a1v[8];
    LOADA(a0v, kt, 0);                      // A h0 in flight during build
    if (kt < 17) BUILD(16384 - PAR, kt + 1);  // next tile -> other buffer
    LOADA(a1v, kt, 1);                      // A h1 in flight during MFMA h0
    AB_MFMA(PAR, 0, a0v);
    AB_MFMA(PAR, 1, a1v);
    __syncthreads();   // build(kt+1) visible to next iter; WAR on buffer PAR
  }

  // Epilogue: 16 FULLY-UNROLLED rounds of 32 o-rows x 128 m fp32 staged in LDS
  // (stride 132 breaks quad-row bank alias), then full float4 lines to global.
  // C/D layout: col(m)=r16, row(o)=quad*4+reg.  MUST be fully unrolled: runtime
  // acc indices demote the accumulator to scratch (R3: 2 GB scratch writes).
  float* lout = (float*)smem;
  const int LSTR = 132;
#pragma unroll
  for (int ob = 0; ob < 16; ++ob) {
    __syncthreads();
    if (wm == (ob >> 2)) {
#pragma unroll
      for (int il = 0; il < 2; ++il) {
        const int i = (ob & 3) * 2 + il;
#pragma unroll
        for (int j = 0; j < 4; ++j) {
          f32x4 v = acc[i][j];
          const int col = wn * 64 + j * 16 + r16;
          const int rb = il * 16 + quad * 4;
          lout[(rb + 0) * LSTR + col] = v[0];
          lout[(rb + 1) * LSTR + col] = v[1];
          lout[(rb + 2) * LSTR + col] = v[2];
          lout[(rb + 3) * LSTR + col] = v[3];
        }
      }
    }
    __syncthreads();
#pragma unroll
    for (int tl = 0; tl < 2; ++tl) {
      const int idx = tl * 512 + tid;       // 1024 f4 = 32 rows x 32 f4
      const int orow = idx >> 5, c4 = idx & 31;
      float4 v = *(const float4*)(lout + orow * LSTR + c4 * 4);
      const int o = ob * 32 + orow;
      const float bv = bias[o];
      v.x += bv; v.y += bv; v.z += bv; v.w += bv;
      const int p = m0 + c4 * 4;
      const int bidx = p / HWN;             // 3136 % 4 == 0 -> no b straddle
      const int hw = p - bidx * HWN;
      *(float4*)(out + (size_t)bidx * ON * HWN + (size_t)o * HWN + hw) = v;
    }
  }
#undef BUILD
#undef LOADA
#undef AB_MFMA
}

extern "C" void kernel_launch(void* const* d_in, const int* in_sizes, int n_in,
                              void* d_out, int out_size, void* d_ws, size_t ws_size,
                              hipStream_t stream) {
  const float* x = (const float*)d_in[0];       // [16,128,56,56]
  const float* w_off = (const float*)d_in[1];   // [18,128]
  const float* b_off = (const float*)d_in[2];   // [18]
  const float* w_conv = (const float*)d_in[3];  // [512,1152]
  const float* b_conv = (const float*)d_in[4];  // [512]
  float* out = (float*)d_out;                   // [16,512,56,56] fp32

  // workspace layout (16B aligned):
  //   xt  : bf16 [B,HW,C]      12,845,056 B @ 0
  //   Wb  : bf16 [512,1152]     1,179,648 B @ 12,845,056
  //   ixy : float2 [M,F]        3,612,672 B @ 14,024,704   (total ~17.6 MB)
  char* ws = (char*)d_ws;
  unsigned short* xt = (unsigned short*)(ws);
  unsigned short* Wb = (unsigned short*)(ws + 12845056);
  float2* ixy = (float2*)(ws + 14024704);

  k_transpose<<<dim3(98, 4, 16), 256, 0, stream>>>(x, xt);
  k_wconv<<<dim3(576), 256, 0, stream>>>((const float4*)w_conv, (ushort4*)Wb);
  k_offsets<<<dim3(196), 256, 0, stream>>>(xt, w_off, b_off, ixy);
  k_fused<<<dim3(392), 512, 0, stream>>>(Wb, xt, ixy, b_conv, out);
}